// Round 17
// baseline (547.573 us; speedup 1.0000x reference)
//
#include <hip/hip_runtime.h>
#include <hip/hip_bf16.h>
#include <math.h>

constexpr int NN  = 51200;   // total nodes
constexpr int EE  = 409600;  // edges (without self loops)
constexpr int BB  = 64;      // graphs
constexpr int APG = 64;      // actions per graph
constexpr int NPG = 800;     // nodes per graph
constexpr int SCAN_N = 2 * NN;
constexpr int NA = BB * APG; // 4096 actions
constexpr int KF = 1056;     // padded MLP input dim (1025 -> 33*32)

typedef __bf16 bf16x8 __attribute__((ext_vector_type(8)));
typedef float f32x4 __attribute__((ext_vector_type(4)));
typedef float f32x2 __attribute__((ext_vector_type(2)));
typedef __attribute__((address_space(1))) const void g_void;
typedef __attribute__((address_space(3))) void l_void;

__device__ __forceinline__ float leaky(float x) { return fmaxf(x, 0.2f * x); }
__device__ __forceinline__ float bflo(unsigned w) { return __uint_as_float(w << 16); }
__device__ __forceinline__ float bfhi(unsigned w) { return __uint_as_float(w & 0xffff0000u); }
__device__ __forceinline__ unsigned short f2b(float x) {
  __hip_bfloat16 h = __float2bfloat16(x);
  unsigned short u;
  __builtin_memcpy(&u, &h, 2);
  return u;
}
__device__ __forceinline__ unsigned pack2(float a, float b) {
  return (unsigned)f2b(a) | ((unsigned)f2b(b) << 16);
}

// ---------------- CSR build ----------------
__global__ void count_kernel(const int* __restrict__ ei, int* cnt) {
  int e = blockIdx.x * blockDim.x + threadIdx.x;
  if (e >= EE) return;
  int s = ei[e], d = ei[EE + e];
  atomicAdd(&cnt[d], 1);
  atomicAdd(&cnt[NN + s], 1);
}

__global__ __launch_bounds__(256) void scan1_kernel(const int* __restrict__ cnt,
                                                    int* __restrict__ rp,
                                                    int* __restrict__ bsum) {
  __shared__ int wsum[4];
  int b = blockIdx.x, t = threadIdx.x;
  int base = b * 1024 + t * 4;
  int4 v = *(const int4*)(cnt + base);
  int s = v.x + v.y + v.z + v.w;
  int lane = t & 63, wv = t >> 6;
  int incl = s;
  for (int off = 1; off < 64; off <<= 1) {
    int u = __shfl_up(incl, off);
    if (lane >= off) incl += u;
  }
  if (lane == 63) wsum[wv] = incl;
  __syncthreads();
  int woff = 0;
  for (int i = 0; i < wv; i++) woff += wsum[i];
  int excl = woff + incl - s;
  rp[base] = excl;
  rp[base + 1] = excl + v.x;
  rp[base + 2] = excl + v.x + v.y;
  rp[base + 3] = excl + v.x + v.y + v.z;
  if (t == 255) bsum[b] = woff + incl;
}

__global__ void scan2_kernel(const int* __restrict__ bsum, int* __restrict__ boff,
                             int* __restrict__ rp) {
  __shared__ int w0;
  int t = threadIdx.x;  // 128 threads
  int v = (t < 100) ? bsum[t] : 0;
  int lane = t & 63;
  int incl = v;
  for (int off = 1; off < 64; off <<= 1) {
    int u = __shfl_up(incl, off);
    if (lane >= off) incl += u;
  }
  if (t == 63) w0 = incl;
  __syncthreads();
  int excl = incl - v + ((t >= 64) ? w0 : 0);
  if (t < 100) boff[t] = excl;
  if (t == 99) rp[SCAN_N] = excl + v;
}

__global__ __launch_bounds__(256) void scan3_kernel(int* __restrict__ rp,
                                                    const int* __restrict__ boff) {
  int b = blockIdx.x;
  int off = boff[b];
  int i = b * 1024 + threadIdx.x * 4;
  int4 v = *(int4*)(rp + i);
  v.x += off; v.y += off; v.z += off; v.w += off;
  *(int4*)(rp + i) = v;
}

__global__ void fill_kernel(const int* __restrict__ ei, const int* __restrict__ rp,
                            int* pos, int* __restrict__ col) {
  int e = blockIdx.x * blockDim.x + threadIdx.x;
  if (e >= EE) return;
  int s = ei[e], d = ei[EE + e];
  int p = atomicAdd(&pos[d], 1);
  col[rp[d] + p] = s;
  int q = atomicAdd(&pos[NN + s], 1);
  col[rp[NN + s] + q] = d;
}

// ------- WA precompute: wa[dir*24 + sd*12 + h*3 + c] = W[c]·a[h] over 64 ch -------
__global__ __launch_bounds__(256) void precomp_kernel(const float* __restrict__ Wf,
                                                      const float* __restrict__ Wb,
                                                      const float* __restrict__ asf,
                                                      const float* __restrict__ adf,
                                                      const float* __restrict__ asb,
                                                      const float* __restrict__ adb,
                                                      float* __restrict__ wa) {
  int wave = (blockIdx.x * blockDim.x + threadIdx.x) >> 6;  // 0..47
  int lane = threadIdx.x & 63;
  if (wave >= 48) return;
  int dir = wave / 24, sd = (wave / 12) % 2, h = (wave / 3) % 4, c = wave % 3;
  const float* W = dir ? Wb : Wf;
  const float* a = dir ? (sd ? adb : asb) : (sd ? adf : asf);
  float v = W[c * 256 + h * 64 + lane] * a[h * 64 + lane];
  for (int off = 1; off < 64; off <<= 1) v += __shfl_xor(v, off);
  if (lane == 0) wa[wave] = v;
}

// ------- layer-1 linear + fused al logits (8 ch/thread, both dirs) ----------
__global__ __launch_bounds__(256) void lin1_kernel(const float* __restrict__ x,
                                                   const float* __restrict__ Wf,
                                                   const float* __restrict__ Wb,
                                                   const float* __restrict__ wa,
                                                   __hip_bfloat16* __restrict__ out,
                                                   float* __restrict__ al_s,
                                                   float* __restrict__ al_d) {
  int idx = blockIdx.x * 256 + threadIdx.x;  // SCAN_N*32
  int n = idx >> 5, grp = idx & 31;
  int dir = (n >= NN) ? 1 : 0;
  int node = dir ? n - NN : n;
  const float* W = dir ? Wb : Wf;
  int c1 = dir ? 2 : 1, c2 = dir ? 4 : 3;
  float f0 = x[node * 5], f1 = x[node * 5 + c1], f2 = x[node * 5 + c2];
  int j0 = grp * 8;
  float v[8];
#pragma unroll
  for (int j = 0; j < 8; j++)
    v[j] = f0 * W[j0 + j] + f1 * W[256 + j0 + j] + f2 * W[512 + j0 + j];
  uint4 u;
  u.x = pack2(v[0], v[1]);
  u.y = pack2(v[2], v[3]);
  u.z = pack2(v[4], v[5]);
  u.w = pack2(v[6], v[7]);
  *(uint4*)(out + (size_t)n * 256 + j0) = u;
  if (grp < 4) {  // head = grp: 3-FMA attention logits from WA table
    const float* ws = wa + dir * 24 + grp * 3;
    const float* wd = wa + dir * 24 + 12 + grp * 3;
    al_s[n * 4 + grp] = f0 * ws[0] + f1 * ws[1] + f2 * ws[2];
    al_d[n * 4 + grp] = f0 * wd[0] + f1 * wd[1] + f2 * wd[2];
  }
}

// ------- fused softmax+SpMM: single pass, unnormalized weights, divide at end -----
// out[d] = (Σ_e w_e x[src_e] + w_self x[d]) / (Σ_e w_e + w_self),
// w = exp(leaky(als[s]+ald[d])).  No max-pass (logits << exp overflow; validated).
template <int ND>
__device__ __forceinline__ void load_dw(const unsigned* p, unsigned* w) {
  if constexpr (ND == 4) {
    uint4 v = *(const uint4*)p;
    w[0] = v.x; w[1] = v.y; w[2] = v.z; w[3] = v.w;
  } else {
    uint2 v = *(const uint2*)p;
    w[0] = v.x; w[1] = v.y;
  }
}
__device__ __forceinline__ f32x2 unpk(unsigned w) {
  f32x2 v;
  v.x = bflo(w);
  v.y = bfhi(w);
  return v;
}

// OUT_SPLIT: layer3 writes bf16 h_node halves (row d%NN, col half d/NN)
template <int HH, int CC, int OUT_SPLIT>
__global__ __launch_bounds__(256) void spmm_kernel(const __hip_bfloat16* __restrict__ xp,
                                                   const float* __restrict__ als,
                                                   const float* __restrict__ ald,
                                                   const int* __restrict__ rp,
                                                   const int* __restrict__ col,
                                                   const float* __restrict__ biasf,
                                                   const float* __restrict__ biasb,
                                                   __hip_bfloat16* __restrict__ out_bf,
                                                   int do_elu) {
  constexpr int HC = HH * CC;
  constexpr int CPL = HC / 32;   // channels per lane (32 lanes per edge)
  constexpr int NW = CPL / 2;    // dwords per lane
  int b = blockIdx.x;
  int xcd = b & 7, q = b >> 3;              // q in [0,3200)
  int g2 = (q / 200) * 8 + xcd;             // [0,128)
  int d = g2 * 800 + (q % 200) * 4 + (threadIdx.x >> 6);
  int off_row = (d >= NN) ? NN : 0;
  const float* bias = (d >= NN) ? biasb : biasf;
  int lane = threadIdx.x & 63;
  int sub = lane & 31, g = lane >> 5;
  int h_l = (sub * CPL) / CC;
  const unsigned* xw = (const unsigned*)xp;
  size_t rowoff = (size_t)sub * NW;
  float ald_l = ald[d * HH + h_l];
  float self_w = __expf(leaky(als[d * HH + h_l] + ald_l));
  f32x2 acc[NW];
#pragma unroll
  for (int j = 0; j < NW; j++) acc[j] = (f32x2)(0.f);
  float wsum = 0.f;
  int beg = rp[d], end = rp[d + 1];
  int deg = end - beg;
  if (g == 0) {  // self loop contribution (weight added once, post-reduction)
    unsigned w[NW];
    load_dw<NW>(xw + (size_t)d * (HC / 2) + rowoff, w);
#pragma unroll
    for (int q2 = 0; q2 < NW; q2++) acc[q2] += self_w * unpk(w[q2]);
  }
  for (int it = 0; it * 4 < deg; it++) {
    int e1 = beg + it * 4 + g;
    int e2 = e1 + 2;
    bool p1 = e1 < end, p2 = e2 < end;
    int ec1 = p1 ? e1 : beg, ec2 = p2 ? e2 : beg;
    int s1 = col[ec1] + off_row, s2 = col[ec2] + off_row;
    float a1 = p1 ? __expf(leaky(als[s1 * HH + h_l] + ald_l)) : 0.f;
    float a2 = p2 ? __expf(leaky(als[s2 * HH + h_l] + ald_l)) : 0.f;
    unsigned w1[NW], w2[NW];
    load_dw<NW>(xw + (size_t)s1 * (HC / 2) + rowoff, w1);
    load_dw<NW>(xw + (size_t)s2 * (HC / 2) + rowoff, w2);
    wsum += a1 + a2;
#pragma unroll
    for (int q2 = 0; q2 < NW; q2++)
      acc[q2] += a1 * unpk(w1[q2]) + a2 * unpk(w2[q2]);
  }
  wsum += __shfl_xor(wsum, 32);
#pragma unroll
  for (int j = 0; j < NW; j++) {
    acc[j].x += __shfl_xor(acc[j].x, 32);
    acc[j].y += __shfl_xor(acc[j].y, 32);
  }
  if (g == 0) {
    float inv = 1.f / (wsum + self_w + 1e-16f);
    float v[CPL];
#pragma unroll
    for (int j = 0; j < NW; j++) {
      v[2 * j] = acc[j].x * inv + bias[sub * CPL + 2 * j];
      v[2 * j + 1] = acc[j].y * inv + bias[sub * CPL + 2 * j + 1];
    }
    if (do_elu) {
#pragma unroll
      for (int j = 0; j < CPL; j++) v[j] = v[j] > 0.f ? v[j] : (__expf(v[j]) - 1.f);
    }
    unsigned* ob;
    if constexpr (OUT_SPLIT) {
      int nd = (d < NN) ? d : d - NN;
      int oo = (d < NN) ? 0 : 64;  // dword offset (128 bf16)
      ob = (unsigned*)out_bf + (size_t)nd * 128 + oo + sub * NW;
    } else {
      ob = (unsigned*)out_bf + (size_t)d * (HC / 2) + rowoff;
    }
#pragma unroll
    for (int q2 = 0; q2 < NW; q2++)
      ob[q2] = pack2(v[2 * q2], v[2 * q2 + 1]);
  }
}

// ------- weight cast + transpose + K-pad, two weight tensors in one launch -------
__global__ void castW2_kernel(const float* __restrict__ W0, const float* __restrict__ W1,
                              __hip_bfloat16* __restrict__ Wt0,
                              __hip_bfloat16* __restrict__ Wt1,
                              int K, int N, int Kp) {
  int idx = blockIdx.x * 256 + threadIdx.x;
  int tot = N * Kp;
  if (idx >= 2 * tot) return;
  const float* W = (idx < tot) ? W0 : W1;
  __hip_bfloat16* Wt = (idx < tot) ? Wt0 : Wt1;
  int i = (idx < tot) ? idx : idx - tot;
  int n = i / Kp, k = i % Kp;
  Wt[i] = (k < K) ? __float2bfloat16(W[(size_t)k * N + n]) : __float2bfloat16(0.f);
}

// ---------------- bf16 MFMA GEMM: C[M,N] = A[M,K] @ Bt[N,K]^T ----------------
template <int EPI, int ALH, int ALCC>
__global__ __launch_bounds__(256) void gemm_mfma(const __hip_bfloat16* __restrict__ A,
                                                 const __hip_bfloat16* __restrict__ Bt0,
                                                 const __hip_bfloat16* __restrict__ Bt1,
                                                 __hip_bfloat16* __restrict__ Cb,
                                                 const float* __restrict__ bias0,
                                                 const float* __restrict__ bias1,
                                                 const float* __restrict__ asv0,
                                                 const float* __restrict__ asv1,
                                                 const float* __restrict__ adv0,
                                                 const float* __restrict__ adv1,
                                                 float* __restrict__ al_s,
                                                 float* __restrict__ al_d,
                                                 int M, int N, int K, int Mhalf) {
  __shared__ __align__(16) __hip_bfloat16 As[128 * 32];
  __shared__ __align__(16) __hip_bfloat16 Bs[128 * 32];
  int t = threadIdx.x;
  int wave = t >> 6, lane = t & 63;
  int wm = (wave >> 1) * 64, wn = (wave & 1) * 64;
  int bm = blockIdx.y * 128, bn = blockIdx.x * 128;
  bool second = bm >= Mhalf;
  const __hip_bfloat16* Bt = second ? Bt1 : Bt0;
  const float* bias = second ? bias1 : bias0;
  const float* asv = second ? asv1 : asv0;
  const float* adv = second ? adv1 : adv0;

  int r0 = t >> 2, c0 = (t & 3) * 8;
  const __hip_bfloat16* Ag0 = A + (size_t)(bm + r0) * K + c0;
  const __hip_bfloat16* Ag1 = A + (size_t)(bm + r0 + 64) * K + c0;
  const __hip_bfloat16* Bg0 = Bt + (size_t)(bn + r0) * K + c0;
  const __hip_bfloat16* Bg1 = Bt + (size_t)(bn + r0 + 64) * K + c0;
  __hip_bfloat16* Asp0 = As + t * 8;
  __hip_bfloat16* Asp1 = As + 64 * 8 * 4 + t * 8;
  __hip_bfloat16* Bsp0 = Bs + t * 8;
  __hip_bfloat16* Bsp1 = Bs + 64 * 8 * 4 + t * 8;

  f32x4 acc[4][4];
#pragma unroll
  for (int i = 0; i < 4; i++)
#pragma unroll
    for (int j = 0; j < 4; j++) acc[i][j] = (f32x4)(0.f);

  int frag_off = (lane & 15) * 32 + (lane >> 4) * 8;
  const __hip_bfloat16* Ab = As + wm * 32 + frag_off;
  const __hip_bfloat16* Bb = Bs + wn * 32 + frag_off;

  for (int k0 = 0; k0 < K; k0 += 32) {
    __syncthreads();
    __builtin_amdgcn_global_load_lds((g_void*)(Ag0 + k0), (l_void*)Asp0, 16, 0, 0);
    __builtin_amdgcn_global_load_lds((g_void*)(Ag1 + k0), (l_void*)Asp1, 16, 0, 0);
    __builtin_amdgcn_global_load_lds((g_void*)(Bg0 + k0), (l_void*)Bsp0, 16, 0, 0);
    __builtin_amdgcn_global_load_lds((g_void*)(Bg1 + k0), (l_void*)Bsp1, 16, 0, 0);
    __syncthreads();
    bf16x8 af[4], bfr[4];
#pragma unroll
    for (int i = 0; i < 4; i++) af[i] = *(const bf16x8*)(Ab + i * 16 * 32);
#pragma unroll
    for (int j = 0; j < 4; j++) bfr[j] = *(const bf16x8*)(Bb + j * 16 * 32);
#pragma unroll
    for (int i = 0; i < 4; i++)
#pragma unroll
      for (int j = 0; j < 4; j++)
        acc[i][j] = __builtin_amdgcn_mfma_f32_16x16x32_bf16(af[i], bfr[j], acc[i][j], 0, 0, 0);
  }

  int cr = (lane >> 4) * 4, cc = lane & 15;

  if constexpr (ALH > 0) {
    int head = (bn + wn) / ALCC;
    float as_c[4], ad_c[4];
#pragma unroll
    for (int j = 0; j < 4; j++) {
      int colx = bn + wn + j * 16 + cc;
      as_c[j] = asv[colx];
      ad_c[j] = adv[colx];
    }
#pragma unroll
    for (int i = 0; i < 4; i++)
#pragma unroll
      for (int r = 0; r < 4; r++) {
        float ps = 0.f, pd = 0.f;
#pragma unroll
        for (int j = 0; j < 4; j++) {
          ps += acc[i][j][r] * as_c[j];
          pd += acc[i][j][r] * ad_c[j];
        }
        ps += __shfl_xor(ps, 1); pd += __shfl_xor(pd, 1);
        ps += __shfl_xor(ps, 2); pd += __shfl_xor(pd, 2);
        ps += __shfl_xor(ps, 4); pd += __shfl_xor(pd, 4);
        ps += __shfl_xor(ps, 8); pd += __shfl_xor(pd, 8);
        if ((lane & 15) == 0) {
          int row = bm + wm + i * 16 + cr + r;
          if (ALCC > 64) {
            atomicAdd(&al_s[row * ALH + head], ps);
            atomicAdd(&al_d[row * ALH + head], pd);
          } else {
            al_s[row * ALH + head] = ps;
            al_d[row * ALH + head] = pd;
          }
        }
      }
  }

#pragma unroll
  for (int i = 0; i < 4; i++)
#pragma unroll
    for (int j = 0; j < 4; j++) {
      int colx = bn + wn + j * 16 + cc;
      float bs = (EPI == 2) ? bias[colx] : 0.f;
#pragma unroll
      for (int r = 0; r < 4; r++) {
        float v = acc[i][j][r];
        if (EPI == 2) v = tanhf(v + bs);
        Cb[(size_t)(bm + wm + i * 16 + cr + r) * N + colx] = __float2bfloat16(v);
      }
    }
}

// ---------------- graph mean pooling (two stage, bf16 h_node) ----------------
__global__ void pool1_kernel(const __hip_bfloat16* __restrict__ h_node,
                             float* __restrict__ part) {
  int g = blockIdx.y, c = blockIdx.x, t = threadIdx.x;  // t over 128 dwords (256 ch)
  const unsigned* base = (const unsigned*)h_node + ((size_t)g * NPG + c * 100) * 128 + t;
  f32x2 s = (f32x2)(0.f);
  for (int i = 0; i < 100; i++) s += unpk(base[(size_t)i * 128]);
  part[(size_t)(g * 8 + c) * 256 + 2 * t] = s.x;
  part[(size_t)(g * 8 + c) * 256 + 2 * t + 1] = s.y;
}

__global__ void pool2_kernel(const float* __restrict__ part, float* __restrict__ g_pool) {
  int g = blockIdx.x, t = threadIdx.x;
  float s = 0.f;
  for (int c = 0; c < 8; c++) s += part[(size_t)(g * 8 + c) * 256 + t];
  g_pool[g * 256 + t] = s * (1.f / NPG);
}

// ---------------- build MLP input features (bf16 h_node -> bf16 feat) -------------
__global__ __launch_bounds__(256) void buildfeat_kernel(const __hip_bfloat16* __restrict__ h_node,
                                                        const float* __restrict__ g_pool,
                                                        const int* __restrict__ actions,
                                                        const float* __restrict__ tabu,
                                                        const int* __restrict__ batch,
                                                        __hip_bfloat16* __restrict__ feat) {
  int a = (blockIdx.x * blockDim.x + threadIdx.x) >> 6;
  int lane = threadIdx.x & 63;
  if (a >= NA) return;
  int n0 = actions[a * 2], n1 = actions[a * 2 + 1];
  int g = batch[n0];
  ushort4 v0 = *(const ushort4*)(h_node + (size_t)n0 * 256 + lane * 4);
  float4 vg = *(const float4*)(g_pool + (size_t)g * 256 + lane * 4);
  ushort4 v1 = *(const ushort4*)(h_node + (size_t)n1 * 256 + lane * 4);
  __hip_bfloat16* fr = feat + (size_t)a * KF;
  ushort4 ug = make_ushort4(f2b(vg.x), f2b(vg.y), f2b(vg.z), f2b(vg.w));
  *(ushort4*)(fr + lane * 4) = v0;
  *(ushort4*)(fr + 256 + lane * 4) = ug;
  *(ushort4*)(fr + 512 + lane * 4) = v1;
  *(ushort4*)(fr + 768 + lane * 4) = ug;
  if (lane < 8) {
    float t0 = (lane == 0) ? tabu[a] : 0.f;
    ushort4 u = make_ushort4(f2b(t0), 0, 0, 0);
    *(ushort4*)(fr + 1024 + lane * 4) = u;
  }
}

// ------- fused head: scores = y @ W4 + b4, then log-softmax + entropy per graph ----
__global__ __launch_bounds__(256) void head_kernel(const __hip_bfloat16* __restrict__ y,
                                                   const float* __restrict__ W4,
                                                   const float* __restrict__ b4,
                                                   float* __restrict__ out) {
  __shared__ float sc[64];
  int g = blockIdx.x;  // graph
  int t = threadIdx.x;
  int a = t >> 2, sub = t & 3;
  int aid = g * 64 + a;
  const unsigned* row = (const unsigned*)(y + (size_t)aid * 256) + sub * 32;
  const float* w = W4 + sub * 64;
  float s = 0.f;
#pragma unroll
  for (int q = 0; q < 32; q++) {
    s += bflo(row[q]) * w[2 * q] + bfhi(row[q]) * w[2 * q + 1];
  }
  s += __shfl_xor(s, 1);
  s += __shfl_xor(s, 2);
  if (sub == 0) sc[a] = s + b4[0];
  __syncthreads();
  if (t < 64) {
    float v = sc[t];
    float m = v;
    for (int off = 1; off < 64; off <<= 1) m = fmaxf(m, __shfl_xor(m, off));
    float ex = expf(v - m);
    float sum = ex;
    for (int off = 1; off < 64; off <<= 1) sum += __shfl_xor(sum, off);
    float lp = v - m - logf(sum);
    out[g * 64 + t] = lp;
    float pe = (ex / sum) * lp;
    for (int off = 1; off < 64; off <<= 1) pe += __shfl_xor(pe, off);
    if (t == 0) out[BB * APG + g] = -pe;
  }
}

extern "C" void kernel_launch(void* const* d_in, const int* in_sizes, int n_in,
                              void* d_out, int out_size, void* d_ws, size_t ws_size,
                              hipStream_t stream) {
  const float* x = (const float*)d_in[0];
  const int* ei = (const int*)d_in[1];
  const int* batch = (const int*)d_in[2];
  const int* actions = (const int*)d_in[3];
  const float* tabu = (const float*)d_in[4];
  const float* fW[3] = {(const float*)d_in[5], (const float*)d_in[9], (const float*)d_in[13]};
  const float* fas[3] = {(const float*)d_in[6], (const float*)d_in[10], (const float*)d_in[14]};
  const float* fad[3] = {(const float*)d_in[7], (const float*)d_in[11], (const float*)d_in[15]};
  const float* fb[3] = {(const float*)d_in[8], (const float*)d_in[12], (const float*)d_in[16]};
  const float* bW[3] = {(const float*)d_in[17], (const float*)d_in[21], (const float*)d_in[25]};
  const float* bas[3] = {(const float*)d_in[18], (const float*)d_in[22], (const float*)d_in[26]};
  const float* bad[3] = {(const float*)d_in[19], (const float*)d_in[23], (const float*)d_in[27]};
  const float* bb[3] = {(const float*)d_in[20], (const float*)d_in[24], (const float*)d_in[28]};
  const float* pW1 = (const float*)d_in[29];
  const float* pb1 = (const float*)d_in[30];
  const float* pW2 = (const float*)d_in[31];
  const float* pb2 = (const float*)d_in[32];
  const float* pW3 = (const float*)d_in[33];
  const float* pb3 = (const float*)d_in[34];
  const float* pW4 = (const float*)d_in[35];
  const float* pb4 = (const float*)d_in[36];
  float* out = (float*)d_out;

  char* ws = (char*)d_ws;
  size_t o = 0;
  auto alloc = [&](size_t bytes) -> void* {
    o = (o + 255) & ~(size_t)255;
    void* p = ws + o;
    o += bytes;
    return p;
  };
  int* cnt = (int*)alloc((size_t)4 * NN * 4);  // cnt[2NN] + pos[2NN]
  int* rp = (int*)alloc((size_t)(SCAN_N + 1) * 4);
  int* col = (int*)alloc(((size_t)2 * EE + 64) * 4);
  int* bsum = (int*)alloc(128 * 4);
  int* boff = (int*)alloc(128 * 4);
  float* al_s = (float*)alloc((size_t)SCAN_N * 4 * 4);  // al_s + al_d contiguous
  float* al_d = (float*)alloc((size_t)SCAN_N * 4 * 4);
  float* wa = (float*)alloc(64 * 4);
  __hip_bfloat16* xp = (__hip_bfloat16*)alloc((size_t)SCAN_N * 256 * 2);    // both dirs
  __hip_bfloat16* bufA = (__hip_bfloat16*)alloc((size_t)SCAN_N * 256 * 2);  // spmm out
  __hip_bfloat16* h_node = (__hip_bfloat16*)alloc((size_t)NN * 256 * 2);
  __hip_bfloat16* wt0 = (__hip_bfloat16*)alloc((size_t)256 * KF * 2);
  __hip_bfloat16* wt1 = (__hip_bfloat16*)alloc((size_t)256 * KF * 2);
  float* part = (float*)alloc((size_t)BB * 8 * 256 * 4);
  float* g_pool = (float*)alloc((size_t)BB * 256 * 4);
  // MLP scratch aliased onto xp (dead after last spmm)
  __hip_bfloat16* feat = xp;
  __hip_bfloat16* y1 = feat + (size_t)NA * KF;
  __hip_bfloat16* y2 = y1 + (size_t)NA * 256;

  // --- CSR build ---
  hipMemsetAsync(cnt, 0, (size_t)4 * NN * 4, stream);
  count_kernel<<<(EE + 255) / 256, 256, 0, stream>>>(ei, cnt);
  scan1_kernel<<<SCAN_N / 1024, 256, 0, stream>>>(cnt, rp, bsum);
  scan2_kernel<<<1, 128, 0, stream>>>(bsum, boff, rp);
  scan3_kernel<<<SCAN_N / 1024, 256, 0, stream>>>(rp, boff);
  fill_kernel<<<(EE + 255) / 256, 256, 0, stream>>>(ei, rp, cnt + 2 * NN, col);

  const int nwb = SCAN_N / 4;  // spmm blocks (merged dirs)

  // layer 1 (fin=3, H=4, C=64) both dirs: WA table + fused linear/al logits
  precomp_kernel<<<12, 256, 0, stream>>>(fW[0], bW[0], fas[0], fad[0], bas[0], bad[0], wa);
  lin1_kernel<<<SCAN_N * 32 / 256, 256, 0, stream>>>(x, fW[0], bW[0], wa, xp, al_s, al_d);
  spmm_kernel<4, 64, 0><<<nwb, 256, 0, stream>>>(xp, al_s, al_d, rp, col,
                                                 fb[0], bb[0], bufA, 1);
  // layer 2 (256 -> H4C64) both dirs, al fused into GEMM epilogue
  castW2_kernel<<<(2 * 256 * 256 + 255) / 256, 256, 0, stream>>>(fW[1], bW[1], wt0, wt1,
                                                                 256, 256, 256);
  gemm_mfma<1, 4, 64><<<dim3(2, SCAN_N / 128), 256, 0, stream>>>(
      bufA, wt0, wt1, xp, nullptr, nullptr, fas[1], bas[1], fad[1], bad[1],
      al_s, al_d, SCAN_N, 256, 256, NN);
  spmm_kernel<4, 64, 0><<<nwb, 256, 0, stream>>>(xp, al_s, al_d, rp, col,
                                                 fb[1], bb[1], bufA, 1);
  // layer 3 (256 -> H1C128, no elu) both dirs -> h_node halves (bf16); al fused
  castW2_kernel<<<(2 * 128 * 256 + 255) / 256, 256, 0, stream>>>(fW[2], bW[2], wt0, wt1,
                                                                 256, 128, 256);
  hipMemsetAsync(al_s, 0, (size_t)2 * SCAN_N * 4, stream);  // al_s + al_d (contiguous)
  gemm_mfma<1, 1, 128><<<dim3(1, SCAN_N / 128), 256, 0, stream>>>(
      bufA, wt0, wt1, xp, nullptr, nullptr, fas[2], bas[2], fad[2], bad[2],
      al_s, al_d, SCAN_N, 128, 256, NN);
  spmm_kernel<1, 128, 1><<<nwb, 256, 0, stream>>>(xp, al_s, al_d, rp, col,
                                                  fb[2], bb[2], h_node, 0);

  pool1_kernel<<<dim3(8, BB), 128, 0, stream>>>(h_node, part);
  pool2_kernel<<<BB, 256, 0, stream>>>(part, g_pool);

  // --- MLP head via MFMA ---
  buildfeat_kernel<<<NA / 4, 256, 0, stream>>>(h_node, g_pool, actions, tabu, batch, feat);
  castW2_kernel<<<(2 * 256 * KF + 255) / 256, 256, 0, stream>>>(pW1, pW1, wt0, wt1,
                                                                1025, 256, KF);
  gemm_mfma<2, 0, 64><<<dim3(2, NA / 128), 256, 0, stream>>>(
      feat, wt0, wt0, y1, pb1, pb1, nullptr, nullptr, nullptr, nullptr,
      nullptr, nullptr, NA, 256, KF, 1 << 30);
  castW2_kernel<<<(2 * 256 * 256 + 255) / 256, 256, 0, stream>>>(pW2, pW3, wt0, wt1,
                                                                 256, 256, 256);
  gemm_mfma<2, 0, 64><<<dim3(2, NA / 128), 256, 0, stream>>>(
      y1, wt0, wt0, y2, pb2, pb2, nullptr, nullptr, nullptr, nullptr,
      nullptr, nullptr, NA, 256, 256, 1 << 30);
  gemm_mfma<2, 0, 64><<<dim3(2, NA / 128), 256, 0, stream>>>(
      y2, wt1, wt1, y1, pb3, pb3, nullptr, nullptr, nullptr, nullptr,
      nullptr, nullptr, NA, 256, 256, 1 << 30);
  head_kernel<<<BB, 256, 0, stream>>>(y1, pW4, pb4, out);
}

// Round 18
// 529.751 us; speedup vs baseline: 1.0336x; 1.0336x over previous
//
#include <hip/hip_runtime.h>
#include <hip/hip_bf16.h>
#include <math.h>

constexpr int NN  = 51200;   // total nodes
constexpr int EE  = 409600;  // edges (without self loops)
constexpr int BB  = 64;      // graphs
constexpr int APG = 64;      // actions per graph
constexpr int NPG = 800;     // nodes per graph
constexpr int SCAN_N = 2 * NN;
constexpr int NA = BB * APG; // 4096 actions
constexpr int KF = 1056;     // padded MLP input dim (1025 -> 33*32)

typedef __bf16 bf16x8 __attribute__((ext_vector_type(8)));
typedef float f32x4 __attribute__((ext_vector_type(4)));
typedef float f32x2 __attribute__((ext_vector_type(2)));
typedef __attribute__((address_space(1))) const void g_void;
typedef __attribute__((address_space(3))) void l_void;

__device__ __forceinline__ float leaky(float x) { return fmaxf(x, 0.2f * x); }
__device__ __forceinline__ float bflo(unsigned w) { return __uint_as_float(w << 16); }
__device__ __forceinline__ float bfhi(unsigned w) { return __uint_as_float(w & 0xffff0000u); }
__device__ __forceinline__ unsigned short f2b(float x) {
  __hip_bfloat16 h = __float2bfloat16(x);
  unsigned short u;
  __builtin_memcpy(&u, &h, 2);
  return u;
}
__device__ __forceinline__ unsigned pack2(float a, float b) {
  return (unsigned)f2b(a) | ((unsigned)f2b(b) << 16);
}

// ---------------- CSR build ----------------
__global__ void count_kernel(const int* __restrict__ ei, int* cnt) {
  int e = blockIdx.x * blockDim.x + threadIdx.x;
  if (e >= EE) return;
  int s = ei[e], d = ei[EE + e];
  atomicAdd(&cnt[d], 1);
  atomicAdd(&cnt[NN + s], 1);
}

__global__ __launch_bounds__(256) void scan1_kernel(const int* __restrict__ cnt,
                                                    int* __restrict__ rp,
                                                    int* __restrict__ bsum) {
  __shared__ int wsum[4];
  int b = blockIdx.x, t = threadIdx.x;
  int base = b * 1024 + t * 4;
  int4 v = *(const int4*)(cnt + base);
  int s = v.x + v.y + v.z + v.w;
  int lane = t & 63, wv = t >> 6;
  int incl = s;
  for (int off = 1; off < 64; off <<= 1) {
    int u = __shfl_up(incl, off);
    if (lane >= off) incl += u;
  }
  if (lane == 63) wsum[wv] = incl;
  __syncthreads();
  int woff = 0;
  for (int i = 0; i < wv; i++) woff += wsum[i];
  int excl = woff + incl - s;
  rp[base] = excl;
  rp[base + 1] = excl + v.x;
  rp[base + 2] = excl + v.x + v.y;
  rp[base + 3] = excl + v.x + v.y + v.z;
  if (t == 255) bsum[b] = woff + incl;
}

__global__ void scan2_kernel(const int* __restrict__ bsum, int* __restrict__ boff,
                             int* __restrict__ rp) {
  __shared__ int w0;
  int t = threadIdx.x;  // 128 threads
  int v = (t < 100) ? bsum[t] : 0;
  int lane = t & 63;
  int incl = v;
  for (int off = 1; off < 64; off <<= 1) {
    int u = __shfl_up(incl, off);
    if (lane >= off) incl += u;
  }
  if (t == 63) w0 = incl;
  __syncthreads();
  int excl = incl - v + ((t >= 64) ? w0 : 0);
  if (t < 100) boff[t] = excl;
  if (t == 99) rp[SCAN_N] = excl + v;
}

__global__ __launch_bounds__(256) void scan3_kernel(int* __restrict__ rp,
                                                    const int* __restrict__ boff) {
  int b = blockIdx.x;
  int off = boff[b];
  int i = b * 1024 + threadIdx.x * 4;
  int4 v = *(int4*)(rp + i);
  v.x += off; v.y += off; v.z += off; v.w += off;
  *(int4*)(rp + i) = v;
}

__global__ void fill_kernel(const int* __restrict__ ei, const int* __restrict__ rp,
                            int* pos, int* __restrict__ col) {
  int e = blockIdx.x * blockDim.x + threadIdx.x;
  if (e >= EE) return;
  int s = ei[e], d = ei[EE + e];
  int p = atomicAdd(&pos[d], 1);
  col[rp[d] + p] = s;
  int q = atomicAdd(&pos[NN + s], 1);
  col[rp[NN + s] + q] = d;
}

// ------- WA precompute: wa[dir*24 + sd*12 + h*3 + c] = W[c]·a[h] over 64 ch -------
__global__ __launch_bounds__(256) void precomp_kernel(const float* __restrict__ Wf,
                                                      const float* __restrict__ Wb,
                                                      const float* __restrict__ asf,
                                                      const float* __restrict__ adf,
                                                      const float* __restrict__ asb,
                                                      const float* __restrict__ adb,
                                                      float* __restrict__ wa) {
  int wave = (blockIdx.x * blockDim.x + threadIdx.x) >> 6;  // 0..47
  int lane = threadIdx.x & 63;
  if (wave >= 48) return;
  int dir = wave / 24, sd = (wave / 12) % 2, h = (wave / 3) % 4, c = wave % 3;
  const float* W = dir ? Wb : Wf;
  const float* a = dir ? (sd ? adb : asb) : (sd ? adf : asf);
  float v = W[c * 256 + h * 64 + lane] * a[h * 64 + lane];
  for (int off = 1; off < 64; off <<= 1) v += __shfl_xor(v, off);
  if (lane == 0) wa[wave] = v;
}

// ------- layer-1 linear + fused al logits (8 ch/thread, both dirs) ----------
__global__ __launch_bounds__(256) void lin1_kernel(const float* __restrict__ x,
                                                   const float* __restrict__ Wf,
                                                   const float* __restrict__ Wb,
                                                   const float* __restrict__ wa,
                                                   __hip_bfloat16* __restrict__ out,
                                                   float* __restrict__ al_s,
                                                   float* __restrict__ al_d) {
  int idx = blockIdx.x * 256 + threadIdx.x;  // SCAN_N*32
  int n = idx >> 5, grp = idx & 31;
  int dir = (n >= NN) ? 1 : 0;
  int node = dir ? n - NN : n;
  const float* W = dir ? Wb : Wf;
  int c1 = dir ? 2 : 1, c2 = dir ? 4 : 3;
  float f0 = x[node * 5], f1 = x[node * 5 + c1], f2 = x[node * 5 + c2];
  int j0 = grp * 8;
  float v[8];
#pragma unroll
  for (int j = 0; j < 8; j++)
    v[j] = f0 * W[j0 + j] + f1 * W[256 + j0 + j] + f2 * W[512 + j0 + j];
  uint4 u;
  u.x = pack2(v[0], v[1]);
  u.y = pack2(v[2], v[3]);
  u.z = pack2(v[4], v[5]);
  u.w = pack2(v[6], v[7]);
  *(uint4*)(out + (size_t)n * 256 + j0) = u;
  if (grp < 4) {  // head = grp: 3-FMA attention logits from WA table
    const float* ws = wa + dir * 24 + grp * 3;
    const float* wd = wa + dir * 24 + 12 + grp * 3;
    al_s[n * 4 + grp] = f0 * ws[0] + f1 * ws[1] + f2 * ws[2];
    al_d[n * 4 + grp] = f0 * wd[0] + f1 * wd[1] + f2 * wd[2];
  }
}

// ------- normalized attention weights per edge, no max-pass (8 lanes/node) --------
template <int HH>
__global__ __launch_bounds__(256) void alpha_kernel(const float* __restrict__ als,
                                                    const float* __restrict__ ald,
                                                    const int* __restrict__ rp,
                                                    const int* __restrict__ col,
                                                    float* __restrict__ alpha,
                                                    float* __restrict__ alpha_self) {
  int b = blockIdx.x;
  int xcd = b & 7, q = b >> 3;              // q in [0,400)
  int g2 = (q / 25) * 8 + xcd;              // [0,128)
  int d = g2 * 800 + (q % 25) * 32 + (threadIdx.x >> 3);
  int slot = threadIdx.x & 7;
  int off_row = (d >= NN) ? NN : 0;
  float ald_loc[HH], self_w[HH];
#pragma unroll
  for (int h = 0; h < HH; h++) {
    ald_loc[h] = ald[d * HH + h];
    self_w[h] = __expf(leaky(als[d * HH + h] + ald_loc[h]));
  }
  int beg = rp[d], end = rp[d + 1];
  int i0 = beg + slot;
  bool have = i0 < end;
  int s0 = col[have ? i0 : beg] + off_row;
  float sm[HH], w0[HH];
#pragma unroll
  for (int h = 0; h < HH; h++) sm[h] = 0.f;
  if (have) {
#pragma unroll
    for (int h = 0; h < HH; h++) {
      w0[h] = __expf(leaky(als[s0 * HH + h] + ald_loc[h]));
      sm[h] += w0[h];
    }
  }
  for (int i = i0 + 8; i < end; i += 8) {  // deg > 8 tail
    int s = col[i] + off_row;
#pragma unroll
    for (int h = 0; h < HH; h++) {
      float w = __expf(leaky(als[s * HH + h] + ald_loc[h]));
      sm[h] += w;
      alpha[(size_t)i * HH + h] = w;
    }
  }
#pragma unroll
  for (int h = 0; h < HH; h++) {
    sm[h] += __shfl_xor(sm[h], 1);
    sm[h] += __shfl_xor(sm[h], 2);
    sm[h] += __shfl_xor(sm[h], 4);
  }
  float inv[HH];
#pragma unroll
  for (int h = 0; h < HH; h++)
    inv[h] = 1.f / (sm[h] + self_w[h] + 1e-16f);
  if (have) {
#pragma unroll
    for (int h = 0; h < HH; h++) alpha[(size_t)i0 * HH + h] = w0[h] * inv[h];
  }
  for (int i = i0 + 8; i < end; i += 8)
#pragma unroll
    for (int h = 0; h < HH; h++) alpha[(size_t)i * HH + h] *= inv[h];
  if (slot == 0) {
#pragma unroll
    for (int h = 0; h < HH; h++)
      alpha_self[d * HH + h] = self_w[h] * inv[h];
  }
}

// ------- SpMM merged dirs, bf16 xp, packed-f32 math (2x32 lanes, 4 edges/iter) -----
template <int ND>
__device__ __forceinline__ void load_dw(const unsigned* p, unsigned* w) {
  if constexpr (ND == 4) {
    uint4 v = *(const uint4*)p;
    w[0] = v.x; w[1] = v.y; w[2] = v.z; w[3] = v.w;
  } else {
    uint2 v = *(const uint2*)p;
    w[0] = v.x; w[1] = v.y;
  }
}
__device__ __forceinline__ f32x2 unpk(unsigned w) {
  f32x2 v;
  v.x = bflo(w);
  v.y = bfhi(w);
  return v;
}

// OUT_SPLIT: layer3 writes bf16 h_node halves (row d%NN, col half d/NN)
template <int HH, int CC, int OUT_SPLIT>
__global__ __launch_bounds__(256) void spmm_kernel(const __hip_bfloat16* __restrict__ xp,
                                                   const float* __restrict__ alpha,
                                                   const float* __restrict__ alpha_self,
                                                   const int* __restrict__ rp,
                                                   const int* __restrict__ col,
                                                   const float* __restrict__ biasf,
                                                   const float* __restrict__ biasb,
                                                   __hip_bfloat16* __restrict__ out_bf,
                                                   int do_elu) {
  constexpr int HC = HH * CC;
  constexpr int CPL = HC / 32;   // channels per lane (32 lanes per edge)
  constexpr int NW = CPL / 2;    // dwords per lane
  int b = blockIdx.x;
  int xcd = b & 7, q = b >> 3;              // q in [0,3200)
  int g2 = (q / 200) * 8 + xcd;             // [0,128)
  int d = g2 * 800 + (q % 200) * 4 + (threadIdx.x >> 6);
  int off_row = (d >= NN) ? NN : 0;
  const float* bias = (d >= NN) ? biasb : biasf;
  int lane = threadIdx.x & 63;
  int sub = lane & 31, g = lane >> 5;
  int h_l = (sub * CPL) / CC;
  const unsigned* xw = (const unsigned*)xp;
  size_t rowoff = (size_t)sub * NW;
  f32x2 acc[NW];
#pragma unroll
  for (int j = 0; j < NW; j++) acc[j] = (f32x2)(0.f);
  int beg = rp[d], end = rp[d + 1];
  int deg = end - beg;
  if (g == 0) {  // self loop
    float a = alpha_self[d * HH + h_l];
    unsigned w[NW];
    load_dw<NW>(xw + (size_t)d * (HC / 2) + rowoff, w);
#pragma unroll
    for (int q2 = 0; q2 < NW; q2++) acc[q2] += a * unpk(w[q2]);
  }
  for (int it = 0; it * 4 < deg; it++) {
    int e1 = beg + it * 4 + g;
    int e2 = e1 + 2;
    bool p1 = e1 < end, p2 = e2 < end;
    int ec1 = p1 ? e1 : beg, ec2 = p2 ? e2 : beg;
    int s1 = col[ec1] + off_row, s2 = col[ec2] + off_row;
    float a1 = p1 ? alpha[(size_t)ec1 * HH + h_l] : 0.f;
    float a2 = p2 ? alpha[(size_t)ec2 * HH + h_l] : 0.f;
    unsigned w1[NW], w2[NW];
    load_dw<NW>(xw + (size_t)s1 * (HC / 2) + rowoff, w1);
    load_dw<NW>(xw + (size_t)s2 * (HC / 2) + rowoff, w2);
#pragma unroll
    for (int q2 = 0; q2 < NW; q2++)
      acc[q2] += a1 * unpk(w1[q2]) + a2 * unpk(w2[q2]);
  }
#pragma unroll
  for (int j = 0; j < NW; j++) {
    acc[j].x += __shfl_xor(acc[j].x, 32);
    acc[j].y += __shfl_xor(acc[j].y, 32);
  }
  if (g == 0) {
    float v[CPL];
#pragma unroll
    for (int j = 0; j < NW; j++) {
      v[2 * j] = acc[j].x + bias[sub * CPL + 2 * j];
      v[2 * j + 1] = acc[j].y + bias[sub * CPL + 2 * j + 1];
    }
    if (do_elu) {
#pragma unroll
      for (int j = 0; j < CPL; j++) v[j] = v[j] > 0.f ? v[j] : (__expf(v[j]) - 1.f);
    }
    unsigned* ob;
    if constexpr (OUT_SPLIT) {
      int nd = (d < NN) ? d : d - NN;
      int oo = (d < NN) ? 0 : 64;  // dword offset (128 bf16)
      ob = (unsigned*)out_bf + (size_t)nd * 128 + oo + sub * NW;
    } else {
      ob = (unsigned*)out_bf + (size_t)d * (HC / 2) + rowoff;
    }
#pragma unroll
    for (int q2 = 0; q2 < NW; q2++)
      ob[q2] = pack2(v[2 * q2], v[2 * q2 + 1]);
  }
}

// ------- weight cast + transpose + K-pad, two weight tensors in one launch -------
__global__ void castW2_kernel(const float* __restrict__ W0, const float* __restrict__ W1,
                              __hip_bfloat16* __restrict__ Wt0,
                              __hip_bfloat16* __restrict__ Wt1,
                              int K, int N, int Kp) {
  int idx = blockIdx.x * 256 + threadIdx.x;
  int tot = N * Kp;
  if (idx >= 2 * tot) return;
  const float* W = (idx < tot) ? W0 : W1;
  __hip_bfloat16* Wt = (idx < tot) ? Wt0 : Wt1;
  int i = (idx < tot) ? idx : idx - tot;
  int n = i / Kp, k = i % Kp;
  Wt[i] = (k < K) ? __float2bfloat16(W[(size_t)k * N + n]) : __float2bfloat16(0.f);
}

// ------- single weight cast + transpose + K-pad -------
__global__ void castW1_kernel(const float* __restrict__ W, __hip_bfloat16* __restrict__ Wt,
                              int K, int N, int Kp) {
  int idx = blockIdx.x * 256 + threadIdx.x;
  if (idx >= N * Kp) return;
  int n = idx / Kp, k = idx % Kp;
  Wt[idx] = (k < K) ? __float2bfloat16(W[(size_t)k * N + n]) : __float2bfloat16(0.f);
}

// ---------------- bf16 MFMA GEMM: C[M,N] = A[M,K] @ Bt[N,K]^T ----------------
template <int EPI, int ALH, int ALCC>
__global__ __launch_bounds__(256) void gemm_mfma(const __hip_bfloat16* __restrict__ A,
                                                 const __hip_bfloat16* __restrict__ Bt0,
                                                 const __hip_bfloat16* __restrict__ Bt1,
                                                 __hip_bfloat16* __restrict__ Cb,
                                                 const float* __restrict__ bias0,
                                                 const float* __restrict__ bias1,
                                                 const float* __restrict__ asv0,
                                                 const float* __restrict__ asv1,
                                                 const float* __restrict__ adv0,
                                                 const float* __restrict__ adv1,
                                                 float* __restrict__ al_s,
                                                 float* __restrict__ al_d,
                                                 int M, int N, int K, int Mhalf) {
  __shared__ __align__(16) __hip_bfloat16 As[128 * 32];
  __shared__ __align__(16) __hip_bfloat16 Bs[128 * 32];
  int t = threadIdx.x;
  int wave = t >> 6, lane = t & 63;
  int wm = (wave >> 1) * 64, wn = (wave & 1) * 64;
  int bm = blockIdx.y * 128, bn = blockIdx.x * 128;
  bool second = bm >= Mhalf;
  const __hip_bfloat16* Bt = second ? Bt1 : Bt0;
  const float* bias = second ? bias1 : bias0;
  const float* asv = second ? asv1 : asv0;
  const float* adv = second ? adv1 : adv0;

  int r0 = t >> 2, c0 = (t & 3) * 8;
  const __hip_bfloat16* Ag0 = A + (size_t)(bm + r0) * K + c0;
  const __hip_bfloat16* Ag1 = A + (size_t)(bm + r0 + 64) * K + c0;
  const __hip_bfloat16* Bg0 = Bt + (size_t)(bn + r0) * K + c0;
  const __hip_bfloat16* Bg1 = Bt + (size_t)(bn + r0 + 64) * K + c0;
  __hip_bfloat16* Asp0 = As + t * 8;
  __hip_bfloat16* Asp1 = As + 64 * 8 * 4 + t * 8;
  __hip_bfloat16* Bsp0 = Bs + t * 8;
  __hip_bfloat16* Bsp1 = Bs + 64 * 8 * 4 + t * 8;

  f32x4 acc[4][4];
#pragma unroll
  for (int i = 0; i < 4; i++)
#pragma unroll
    for (int j = 0; j < 4; j++) acc[i][j] = (f32x4)(0.f);

  int frag_off = (lane & 15) * 32 + (lane >> 4) * 8;
  const __hip_bfloat16* Ab = As + wm * 32 + frag_off;
  const __hip_bfloat16* Bb = Bs + wn * 32 + frag_off;

  for (int k0 = 0; k0 < K; k0 += 32) {
    __syncthreads();
    __builtin_amdgcn_global_load_lds((g_void*)(Ag0 + k0), (l_void*)Asp0, 16, 0, 0);
    __builtin_amdgcn_global_load_lds((g_void*)(Ag1 + k0), (l_void*)Asp1, 16, 0, 0);
    __builtin_amdgcn_global_load_lds((g_void*)(Bg0 + k0), (l_void*)Bsp0, 16, 0, 0);
    __builtin_amdgcn_global_load_lds((g_void*)(Bg1 + k0), (l_void*)Bsp1, 16, 0, 0);
    __syncthreads();
    bf16x8 af[4], bfr[4];
#pragma unroll
    for (int i = 0; i < 4; i++) af[i] = *(const bf16x8*)(Ab + i * 16 * 32);
#pragma unroll
    for (int j = 0; j < 4; j++) bfr[j] = *(const bf16x8*)(Bb + j * 16 * 32);
#pragma unroll
    for (int i = 0; i < 4; i++)
#pragma unroll
      for (int j = 0; j < 4; j++)
        acc[i][j] = __builtin_amdgcn_mfma_f32_16x16x32_bf16(af[i], bfr[j], acc[i][j], 0, 0, 0);
  }

  int cr = (lane >> 4) * 4, cc = lane & 15;

  if constexpr (ALH > 0) {
    int head = (bn + wn) / ALCC;
    float as_c[4], ad_c[4];
#pragma unroll
    for (int j = 0; j < 4; j++) {
      int colx = bn + wn + j * 16 + cc;
      as_c[j] = asv[colx];
      ad_c[j] = adv[colx];
    }
#pragma unroll
    for (int i = 0; i < 4; i++)
#pragma unroll
      for (int r = 0; r < 4; r++) {
        float ps = 0.f, pd = 0.f;
#pragma unroll
        for (int j = 0; j < 4; j++) {
          ps += acc[i][j][r] * as_c[j];
          pd += acc[i][j][r] * ad_c[j];
        }
        ps += __shfl_xor(ps, 1); pd += __shfl_xor(pd, 1);
        ps += __shfl_xor(ps, 2); pd += __shfl_xor(pd, 2);
        ps += __shfl_xor(ps, 4); pd += __shfl_xor(pd, 4);
        ps += __shfl_xor(ps, 8); pd += __shfl_xor(pd, 8);
        if ((lane & 15) == 0) {
          int row = bm + wm + i * 16 + cr + r;
          if (ALCC > 64) {
            atomicAdd(&al_s[row * ALH + head], ps);
            atomicAdd(&al_d[row * ALH + head], pd);
          } else {
            al_s[row * ALH + head] = ps;
            al_d[row * ALH + head] = pd;
          }
        }
      }
  }

#pragma unroll
  for (int i = 0; i < 4; i++)
#pragma unroll
    for (int j = 0; j < 4; j++) {
      int colx = bn + wn + j * 16 + cc;
      float bs = (EPI == 2) ? bias[colx] : 0.f;
#pragma unroll
      for (int r = 0; r < 4; r++) {
        float v = acc[i][j][r];
        if (EPI == 2) v = tanhf(v + bs);
        Cb[(size_t)(bm + wm + i * 16 + cr + r) * N + colx] = __float2bfloat16(v);
      }
    }
}

// ---------------- graph mean pooling (two stage, bf16 h_node) ----------------
__global__ void pool1_kernel(const __hip_bfloat16* __restrict__ h_node,
                             float* __restrict__ part) {
  int g = blockIdx.y, c = blockIdx.x, t = threadIdx.x;  // t over 128 dwords (256 ch)
  const unsigned* base = (const unsigned*)h_node + ((size_t)g * NPG + c * 100) * 128 + t;
  f32x2 s = (f32x2)(0.f);
  for (int i = 0; i < 100; i++) s += unpk(base[(size_t)i * 128]);
  part[(size_t)(g * 8 + c) * 256 + 2 * t] = s.x;
  part[(size_t)(g * 8 + c) * 256 + 2 * t + 1] = s.y;
}

__global__ void pool2_kernel(const float* __restrict__ part, float* __restrict__ g_pool) {
  int g = blockIdx.x, t = threadIdx.x;
  float s = 0.f;
  for (int c = 0; c < 8; c++) s += part[(size_t)(g * 8 + c) * 256 + t];
  g_pool[g * 256 + t] = s * (1.f / NPG);
}

// ---------------- build MLP input features (bf16 h_node -> bf16 feat) -------------
__global__ __launch_bounds__(256) void buildfeat_kernel(const __hip_bfloat16* __restrict__ h_node,
                                                        const float* __restrict__ g_pool,
                                                        const int* __restrict__ actions,
                                                        const float* __restrict__ tabu,
                                                        const int* __restrict__ batch,
                                                        __hip_bfloat16* __restrict__ feat) {
  int a = (blockIdx.x * blockDim.x + threadIdx.x) >> 6;
  int lane = threadIdx.x & 63;
  if (a >= NA) return;
  int n0 = actions[a * 2], n1 = actions[a * 2 + 1];
  int g = batch[n0];
  ushort4 v0 = *(const ushort4*)(h_node + (size_t)n0 * 256 + lane * 4);
  float4 vg = *(const float4*)(g_pool + (size_t)g * 256 + lane * 4);
  ushort4 v1 = *(const ushort4*)(h_node + (size_t)n1 * 256 + lane * 4);
  __hip_bfloat16* fr = feat + (size_t)a * KF;
  ushort4 ug = make_ushort4(f2b(vg.x), f2b(vg.y), f2b(vg.z), f2b(vg.w));
  *(ushort4*)(fr + lane * 4) = v0;
  *(ushort4*)(fr + 256 + lane * 4) = ug;
  *(ushort4*)(fr + 512 + lane * 4) = v1;
  *(ushort4*)(fr + 768 + lane * 4) = ug;
  if (lane < 8) {
    float t0 = (lane == 0) ? tabu[a] : 0.f;
    ushort4 u = make_ushort4(f2b(t0), 0, 0, 0);
    *(ushort4*)(fr + 1024 + lane * 4) = u;
  }
}

// ------- fused head: scores = y @ W4 + b4, then log-softmax + entropy per graph ----
__global__ __launch_bounds__(256) void head_kernel(const __hip_bfloat16* __restrict__ y,
                                                   const float* __restrict__ W4,
                                                   const float* __restrict__ b4,
                                                   float* __restrict__ out) {
  __shared__ float sc[64];
  int g = blockIdx.x;  // graph
  int t = threadIdx.x;
  int a = t >> 2, sub = t & 3;
  int aid = g * 64 + a;
  const unsigned* row = (const unsigned*)(y + (size_t)aid * 256) + sub * 32;
  const float* w = W4 + sub * 64;
  float s = 0.f;
#pragma unroll
  for (int q = 0; q < 32; q++) {
    s += bflo(row[q]) * w[2 * q] + bfhi(row[q]) * w[2 * q + 1];
  }
  s += __shfl_xor(s, 1);
  s += __shfl_xor(s, 2);
  if (sub == 0) sc[a] = s + b4[0];
  __syncthreads();
  if (t < 64) {
    float v = sc[t];
    float m = v;
    for (int off = 1; off < 64; off <<= 1) m = fmaxf(m, __shfl_xor(m, off));
    float ex = expf(v - m);
    float sum = ex;
    for (int off = 1; off < 64; off <<= 1) sum += __shfl_xor(sum, off);
    float lp = v - m - logf(sum);
    out[g * 64 + t] = lp;
    float pe = (ex / sum) * lp;
    for (int off = 1; off < 64; off <<= 1) pe += __shfl_xor(pe, off);
    if (t == 0) out[BB * APG + g] = -pe;
  }
}

extern "C" void kernel_launch(void* const* d_in, const int* in_sizes, int n_in,
                              void* d_out, int out_size, void* d_ws, size_t ws_size,
                              hipStream_t stream) {
  const float* x = (const float*)d_in[0];
  const int* ei = (const int*)d_in[1];
  const int* batch = (const int*)d_in[2];
  const int* actions = (const int*)d_in[3];
  const float* tabu = (const float*)d_in[4];
  const float* fW[3] = {(const float*)d_in[5], (const float*)d_in[9], (const float*)d_in[13]};
  const float* fas[3] = {(const float*)d_in[6], (const float*)d_in[10], (const float*)d_in[14]};
  const float* fad[3] = {(const float*)d_in[7], (const float*)d_in[11], (const float*)d_in[15]};
  const float* fb[3] = {(const float*)d_in[8], (const float*)d_in[12], (const float*)d_in[16]};
  const float* bW[3] = {(const float*)d_in[17], (const float*)d_in[21], (const float*)d_in[25]};
  const float* bas[3] = {(const float*)d_in[18], (const float*)d_in[22], (const float*)d_in[26]};
  const float* bad[3] = {(const float*)d_in[19], (const float*)d_in[23], (const float*)d_in[27]};
  const float* bb[3] = {(const float*)d_in[20], (const float*)d_in[24], (const float*)d_in[28]};
  const float* pW1 = (const float*)d_in[29];
  const float* pb1 = (const float*)d_in[30];
  const float* pW2 = (const float*)d_in[31];
  const float* pb2 = (const float*)d_in[32];
  const float* pW3 = (const float*)d_in[33];
  const float* pb3 = (const float*)d_in[34];
  const float* pW4 = (const float*)d_in[35];
  const float* pb4 = (const float*)d_in[36];
  float* out = (float*)d_out;

  char* ws = (char*)d_ws;
  size_t o = 0;
  auto alloc = [&](size_t bytes) -> void* {
    o = (o + 255) & ~(size_t)255;
    void* p = ws + o;
    o += bytes;
    return p;
  };
  int* cnt = (int*)alloc((size_t)4 * NN * 4);  // cnt[2NN] + pos[2NN]
  int* rp = (int*)alloc((size_t)(SCAN_N + 1) * 4);
  int* col = (int*)alloc(((size_t)2 * EE + 64) * 4);
  int* bsum = (int*)alloc(128 * 4);
  int* boff = (int*)alloc(128 * 4);
  float* al_s = (float*)alloc((size_t)SCAN_N * 4 * 4);  // al_s + al_d contiguous
  float* al_d = (float*)alloc((size_t)SCAN_N * 4 * 4);
  float* alpha = (float*)alloc((size_t)2 * EE * 4 * 4);
  float* alpha_self = (float*)alloc((size_t)SCAN_N * 4 * 4);
  float* wa = (float*)alloc(64 * 4);
  __hip_bfloat16* xp = (__hip_bfloat16*)alloc((size_t)SCAN_N * 256 * 2);    // both dirs
  __hip_bfloat16* bufA = (__hip_bfloat16*)alloc((size_t)SCAN_N * 256 * 2);  // spmm out
  __hip_bfloat16* h_node = (__hip_bfloat16*)alloc((size_t)NN * 256 * 2);
  __hip_bfloat16* wt0 = (__hip_bfloat16*)alloc((size_t)256 * KF * 2);
  __hip_bfloat16* wt1 = (__hip_bfloat16*)alloc((size_t)256 * KF * 2);
  float* part = (float*)alloc((size_t)BB * 8 * 256 * 4);
  float* g_pool = (float*)alloc((size_t)BB * 256 * 4);
  // MLP scratch aliased onto xp (dead after last spmm)
  __hip_bfloat16* feat = xp;
  __hip_bfloat16* y1 = feat + (size_t)NA * KF;
  __hip_bfloat16* y2 = y1 + (size_t)NA * 256;

  // --- CSR build ---
  hipMemsetAsync(cnt, 0, (size_t)4 * NN * 4, stream);
  count_kernel<<<(EE + 255) / 256, 256, 0, stream>>>(ei, cnt);
  scan1_kernel<<<SCAN_N / 1024, 256, 0, stream>>>(cnt, rp, bsum);
  scan2_kernel<<<1, 128, 0, stream>>>(bsum, boff, rp);
  scan3_kernel<<<SCAN_N / 1024, 256, 0, stream>>>(rp, boff);
  fill_kernel<<<(EE + 255) / 256, 256, 0, stream>>>(ei, rp, cnt + 2 * NN, col);

  const int nwb = SCAN_N / 4;        // spmm blocks (merged)
  const int nab = SCAN_N * 8 / 256;  // alpha blocks (merged)

  // layer 1 (fin=3, H=4, C=64) both dirs: WA table + fused linear/al logits
  precomp_kernel<<<12, 256, 0, stream>>>(fW[0], bW[0], fas[0], fad[0], bas[0], bad[0], wa);
  lin1_kernel<<<SCAN_N * 32 / 256, 256, 0, stream>>>(x, fW[0], bW[0], wa, xp, al_s, al_d);
  alpha_kernel<4><<<nab, 256, 0, stream>>>(al_s, al_d, rp, col, alpha, alpha_self);
  spmm_kernel<4, 64, 0><<<nwb, 256, 0, stream>>>(xp, alpha, alpha_self, rp, col,
                                                 fb[0], bb[0], bufA, 1);
  // layer 2 (256 -> H4C64) both dirs, al fused into GEMM epilogue
  castW2_kernel<<<(2 * 256 * 256 + 255) / 256, 256, 0, stream>>>(fW[1], bW[1], wt0, wt1,
                                                                 256, 256, 256);
  gemm_mfma<1, 4, 64><<<dim3(2, SCAN_N / 128), 256, 0, stream>>>(
      bufA, wt0, wt1, xp, nullptr, nullptr, fas[1], bas[1], fad[1], bad[1],
      al_s, al_d, SCAN_N, 256, 256, NN);
  alpha_kernel<4><<<nab, 256, 0, stream>>>(al_s, al_d, rp, col, alpha, alpha_self);
  spmm_kernel<4, 64, 0><<<nwb, 256, 0, stream>>>(xp, alpha, alpha_self, rp, col,
                                                 fb[1], bb[1], bufA, 1);
  // layer 3 (256 -> H1C128, no elu) both dirs -> h_node halves (bf16); al fused
  castW2_kernel<<<(2 * 128 * 256 + 255) / 256, 256, 0, stream>>>(fW[2], bW[2], wt0, wt1,
                                                                 256, 128, 256);
  hipMemsetAsync(al_s, 0, (size_t)2 * SCAN_N * 4, stream);  // al_s + al_d (contiguous)
  gemm_mfma<1, 1, 128><<<dim3(1, SCAN_N / 128), 256, 0, stream>>>(
      bufA, wt0, wt1, xp, nullptr, nullptr, fas[2], bas[2], fad[2], bad[2],
      al_s, al_d, SCAN_N, 128, 256, NN);
  alpha_kernel<1><<<nab, 256, 0, stream>>>(al_s, al_d, rp, col, alpha, alpha_self);
  spmm_kernel<1, 128, 1><<<nwb, 256, 0, stream>>>(xp, alpha, alpha_self, rp, col,
                                                  fb[2], bb[2], h_node, 0);

  pool1_kernel<<<dim3(8, BB), 128, 0, stream>>>(h_node, part);
  pool2_kernel<<<BB, 256, 0, stream>>>(part, g_pool);

  // --- MLP head via MFMA ---
  buildfeat_kernel<<<NA / 4, 256, 0, stream>>>(h_node, g_pool, actions, tabu, batch, feat);
  castW1_kernel<<<(256 * KF + 255) / 256, 256, 0, stream>>>(pW1, wt0, 1025, 256, KF);
  gemm_mfma<2, 0, 64><<<dim3(2, NA / 128), 256, 0, stream>>>(
      feat, wt0, wt0, y1, pb1, pb1, nullptr, nullptr, nullptr, nullptr,
      nullptr, nullptr, NA, 256, KF, 1 << 30);
  castW2_kernel<<<(2 * 256 * 256 + 255) / 256, 256, 0, stream>>>(pW2, pW3, wt0, wt1,
                                                                 256, 256, 256);
  gemm_mfma<2, 0, 64><<<dim3(2, NA / 128), 256, 0, stream>>>(
      y1, wt0, wt0, y2, pb2, pb2, nullptr, nullptr, nullptr, nullptr,
      nullptr, nullptr, NA, 256, 256, 1 << 30);
  gemm_mfma<2, 0, 64><<<dim3(2, NA / 128), 256, 0, stream>>>(
      y2, wt1, wt1, y1, pb3, pb3, nullptr, nullptr, nullptr, nullptr,
      nullptr, nullptr, NA, 256, 256, 1 << 30);
  head_kernel<<<BB, 256, 0, stream>>>(y1, pW4, pb4, out);
}